// Round 6
// baseline (130.635 us; speedup 1.0000x reference)
//
#include <hip/hip_runtime.h>

#define IN_F  8192
#define OUT_F 8192
#define BATCH 16
#define KSPLIT 16
#define KCHUNK (IN_F / KSPLIT)   // 512 k per block
#define KSTEP  128               // k per inner step (64 lanes x 2)
#define NSTEPS (KCHUNK / KSTEP)  // 4
#define THREADS 256
#define ROWS_PER_BLOCK 16        // 4 waves x 4 rows/thread

typedef const __attribute__((address_space(1))) unsigned int g_u32;
typedef __attribute__((address_space(3))) unsigned int s_u32;

// out[b][o] = bias[o]  (re-inits the atomic accumulator every call)
__global__ __launch_bounds__(256)
void init_out_kernel(const float* __restrict__ bias, float* __restrict__ out)
{
    const int i = blockIdx.x * 256 + threadIdx.x;
    out[i] = bias[i & (OUT_F - 1)];
}

__global__ __launch_bounds__(THREADS, 4)
void gptq_main_kernel(const float* __restrict__ x,
                      const int*  __restrict__ qw,
                      const float* __restrict__ scale,
                      float* __restrict__ out)
{
    // whole x panel for this block's k-chunk: 16 x 512 f32 = 32 KB, staged ONCE
    __shared__ __align__(16) float xs[BATCH][KCHUNK];

    const int tid  = threadIdx.x;
    const int lane = tid & 63;
    const int wave = tid >> 6;
    const int kidx   = blockIdx.x & (KSPLIT - 1);
    const int rowgrp = blockIdx.x >> 4;
    const int row0 = rowgrp * ROWS_PER_BLOCK + wave * 4;
    const int k0   = kidx * KCHUNK;

    // stage x panel: 32 chunks of 1 KB; wave w stages chunks [8w, 8w+8).
    // chunk c = row c/2, half c%2 (each row is 2 KB). LDS dest is linear
    // (base + lane*16) as gload_lds requires.
    #pragma unroll
    for (int j = 0; j < 8; ++j) {
        const int c = wave * 8 + j;
        const int r = c >> 1, h = c & 1;
        __builtin_amdgcn_global_load_lds(
            (g_u32*)(x + (size_t)r * IN_F + k0 + h * 256 + lane * 4),
            (s_u32*)&xs[r][h * 256 + lane * 4], 16, 0, 0);
    }
    __syncthreads();   // the ONLY barrier in the kernel

    float acc[64];
    #pragma unroll
    for (int i = 0; i < 64; ++i) acc[i] = 0.0f;

    const int* qsrc = qw + (size_t)row0 * IN_F + k0 + lane * 2;

    // barrier-free K-loop: plain loads, full unroll — compiler is free to
    // hoist step s+1/s+2 weight loads over step-s FMAs (nothing blocks it)
    #pragma unroll
    for (int s = 0; s < NSTEPS; ++s) {
        int2 wv[4];
        #pragma unroll
        for (int r = 0; r < 4; ++r)
            wv[r] = *reinterpret_cast<const int2*>(qsrc + (size_t)r * IN_F + s * KSTEP);

        float wf[4][2];
        #pragma unroll
        for (int r = 0; r < 4; ++r) {
            wf[r][0] = (float)wv[r].x;   // int4-valued, exact in fp32
            wf[r][1] = (float)wv[r].y;
        }

        #pragma unroll
        for (int b = 0; b < BATCH; ++b) {
            const float2 xv = *reinterpret_cast<const float2*>(&xs[b][s * KSTEP + lane * 2]);
            #pragma unroll
            for (int r = 0; r < 4; ++r) {
                acc[r * 16 + b] += wf[r][0] * xv.x;
                acc[r * 16 + b] += wf[r][1] * xv.y;
            }
        }
    }

    // recursive-halving reduction across the 64-lane k-split
    #pragma unroll
    for (int m = 1, half = 32; m <= 32; m <<= 1, half >>= 1) {
        const bool hi = (lane & m) != 0;
        #pragma unroll
        for (int i = 0; i < half; ++i) {
            const float send = hi ? acc[i] : acc[half + i];
            const float recv = __shfl_xor(send, m, 64);
            const float keep = hi ? acc[half + i] : acc[i];
            acc[i] = keep + recv;
        }
    }

    const int idx = ((lane & 1)  << 5) | ((lane & 2)  << 3) | ((lane & 4)  << 1)
                  | ((lane & 8)  >> 1) | ((lane & 16) >> 3) | ((lane & 32) >> 5);
    const int r = idx >> 4;        // row within wave's 4
    const int b = idx & 15;        // batch
    const int o = row0 + r;

    atomicAdd(out + (size_t)b * OUT_F + o, acc[0] * scale[0]);
}

extern "C" void kernel_launch(void* const* d_in, const int* in_sizes, int n_in,
                              void* d_out, int out_size, void* d_ws, size_t ws_size,
                              hipStream_t stream) {
    const float* x     = (const float*)d_in[0];
    const int*   qw    = (const int*)d_in[1];
    const float* scale = (const float*)d_in[2];
    const float* bias  = (const float*)d_in[3];
    float*       out   = (float*)d_out;

    init_out_kernel<<<(BATCH * OUT_F) / 256, 256, 0, stream>>>(bias, out);

    dim3 grid((OUT_F / ROWS_PER_BLOCK) * KSPLIT);   // 512 x 16 = 8192 blocks
    gptq_main_kernel<<<grid, THREADS, 0, stream>>>(x, qw, scale, out);
}

// Round 7
// 76.162 us; speedup vs baseline: 1.7152x; 1.7152x over previous
//
#include <hip/hip_runtime.h>
#include <hip/hip_bf16.h>

#define IN_F  8192
#define OUT_F 8192
#define BATCH 16
#define KSPLIT 4
#define KCHUNK (IN_F / KSPLIT)   // 2048 k per block
#define KSTEP  128               // k per inner step (64 lanes x 2)
#define NSTEPS (KCHUNK / KSTEP)  // 16
#define THREADS 512              // 8 waves x 4 rows = 32 rows/block
#define ROWS_PER_BLOCK 32

// out[b][o] = bias[o]  (re-inits the atomic accumulator every call)
__global__ __launch_bounds__(256)
void init_out_kernel(const float* __restrict__ bias, float* __restrict__ out)
{
    const int i = blockIdx.x * 256 + threadIdx.x;
    out[i] = bias[i & (OUT_F - 1)];
}

__global__ __launch_bounds__(THREADS, 4)   // cap 128 VGPR -> 2 blocks/CU
void gptq_main_kernel(const float* __restrict__ x,
                      const int*  __restrict__ qw,
                      const float* __restrict__ scale,
                      float* __restrict__ out)
{
    // whole x panel (bf16) for this block's k-chunk: 16 x 2048 x 2B = 64 KB
    __shared__ __align__(16) unsigned short xs[BATCH][KCHUNK];

    const int tid  = threadIdx.x;
    const int lane = tid & 63;
    const int wave = tid >> 6;
    const int kidx   = blockIdx.x & (KSPLIT - 1);
    const int rowgrp = blockIdx.x >> 2;
    const int row0 = rowgrp * ROWS_PER_BLOCK + wave * 4;
    const int k0   = kidx * KCHUNK;

    // ---- stage x panel once: each row is 2048 f32 = 512 threads x float4 ----
    // coalesced 16B/lane loads; bf16 round-to-nearest-even via __float2bfloat16
    #pragma unroll
    for (int r = 0; r < BATCH; ++r) {
        const float4 v = *reinterpret_cast<const float4*>(x + (size_t)r * IN_F + k0 + tid * 4);
        ushort4 p;
        p.x = __bfloat16_as_ushort(__float2bfloat16(v.x));
        p.y = __bfloat16_as_ushort(__float2bfloat16(v.y));
        p.z = __bfloat16_as_ushort(__float2bfloat16(v.z));
        p.w = __bfloat16_as_ushort(__float2bfloat16(v.w));
        *reinterpret_cast<ushort4*>(&xs[r][tid * 4]) = p;
    }
    __syncthreads();   // the ONLY barrier; xs is read-only afterwards

    float acc[64];
    #pragma unroll
    for (int i = 0; i < 64; ++i) acc[i] = 0.0f;

    const int* qsrc = qw + (size_t)row0 * IN_F + k0 + lane * 2;

    // prologue prefetch: step-0 weights
    int2 wcur[4];
    #pragma unroll
    for (int r = 0; r < 4; ++r)
        wcur[r] = *reinterpret_cast<const int2*>(qsrc + (size_t)r * IN_F);

    int koff = KSTEP;  // next step's k offset

    #pragma unroll 1   // forbid cross-step hoisting: bounded regs, 1-step prefetch
    for (int s = 0; s < NSTEPS; ++s) {
        // prefetch next step's weights (register double-buffer)
        int2 wnext[4];
        if (s + 1 < NSTEPS) {
            #pragma unroll
            for (int r = 0; r < 4; ++r)
                wnext[r] = *reinterpret_cast<const int2*>(qsrc + (size_t)r * IN_F + koff);
        }

        float wf[4][2];
        #pragma unroll
        for (int r = 0; r < 4; ++r) {
            wf[r][0] = (float)wcur[r].x;   // int4-valued, exact in fp32
            wf[r][1] = (float)wcur[r].y;
        }

        // 16 ds_read_b32 (2 bf16 each) + 32 unpack + 128 FMA per thread
        const int kx = koff - KSTEP + lane * 2;
        #pragma unroll
        for (int b = 0; b < BATCH; ++b) {
            const unsigned int v = *reinterpret_cast<const unsigned int*>(&xs[b][kx]);
            const float xlo = __uint_as_float(v << 16);          // element k   (low short)
            const float xhi = __uint_as_float(v & 0xffff0000u);  // element k+1 (high short)
            #pragma unroll
            for (int r = 0; r < 4; ++r) {
                acc[r * 16 + b] += wf[r][0] * xlo;
                acc[r * 16 + b] += wf[r][1] * xhi;
            }
        }

        #pragma unroll
        for (int r = 0; r < 4; ++r) wcur[r] = wnext[r];
        koff += KSTEP;
    }

    // ---- recursive-halving butterfly across the 64-lane k-split ----
    #pragma unroll
    for (int m = 1, half = 32; m <= 32; m <<= 1, half >>= 1) {
        const bool hi = (lane & m) != 0;
        #pragma unroll
        for (int i = 0; i < half; ++i) {
            const float send = hi ? acc[i] : acc[half + i];
            const float recv = __shfl_xor(send, m, 64);
            const float keep = hi ? acc[half + i] : acc[i];
            acc[i] = keep + recv;
        }
    }

    const int idx = ((lane & 1)  << 5) | ((lane & 2)  << 3) | ((lane & 4)  << 1)
                  | ((lane & 8)  >> 1) | ((lane & 16) >> 3) | ((lane & 32) >> 5);
    const int r = idx >> 4;        // row within wave's 4
    const int b = idx & 15;        // batch
    const int o = row0 + r;

    atomicAdd(out + (size_t)b * OUT_F + o, acc[0] * scale[0]);
}

extern "C" void kernel_launch(void* const* d_in, const int* in_sizes, int n_in,
                              void* d_out, int out_size, void* d_ws, size_t ws_size,
                              hipStream_t stream) {
    const float* x     = (const float*)d_in[0];
    const int*   qw    = (const int*)d_in[1];
    const float* scale = (const float*)d_in[2];
    const float* bias  = (const float*)d_in[3];
    float*       out   = (float*)d_out;

    init_out_kernel<<<(BATCH * OUT_F) / 256, 256, 0, stream>>>(bias, out);

    dim3 grid((OUT_F / ROWS_PER_BLOCK) * KSPLIT);   // 256 x 4 = 1024 blocks
    gptq_main_kernel<<<grid, THREADS, 0, stream>>>(x, qw, scale, out);
}

// Round 8
// 54.714 us; speedup vs baseline: 2.3876x; 1.3920x over previous
//
#include <hip/hip_runtime.h>
#include <hip/hip_bf16.h>

#define IN_F  8192
#define OUT_F 8192
#define BATCH 16
#define KSPLIT 8
#define KCHUNK (IN_F / KSPLIT)     // 1024 k per block
#define NSTEPS (KCHUNK / 32)       // 32 mfma k-steps
#define THREADS 256                // 4 waves
#define ROWS_PER_BLOCK 64          // 4 waves x 16 rows
#define XPAD 8
#define XSTRIDE (KCHUNK + XPAD)    // 1032 bf16 -> row-to-row bank shift of 4

typedef __attribute__((ext_vector_type(8))) short bf16x8;
typedef __attribute__((ext_vector_type(4))) float f32x4;

// out[b][o] = bias[o]  (re-inits the atomic accumulator every call)
__global__ __launch_bounds__(256)
void init_out_kernel(const float* __restrict__ bias, float* __restrict__ out)
{
    const int i = blockIdx.x * 256 + threadIdx.x;
    out[i] = bias[i & (OUT_F - 1)];
}

__global__ __launch_bounds__(THREADS, 4)
void gptq_mfma_kernel(const float* __restrict__ x,
                      const int*  __restrict__ qw,
                      const float* __restrict__ scale,
                      float* __restrict__ out)
{
    // x panel (bf16) for this block's k-chunk: staged ONCE, read-only after
    __shared__ __align__(16) unsigned short xs[BATCH][XSTRIDE];   // ~33 KB

    const int tid  = threadIdx.x;
    const int lane = tid & 63;
    const int wave = tid >> 6;
    const int mn   = lane & 15;        // A: batch row m   B: out-row col n
    const int kgrp = lane >> 4;        // k-group 0..3
    const int kidx = blockIdx.x & (KSPLIT - 1);
    const int row0 = (blockIdx.x >> 3) * ROWS_PER_BLOCK + wave * 16;
    const int k0   = kidx * KCHUNK;

    // ---- stage x panel once: row r = 1024 f32 = 256 threads x float4 ----
    #pragma unroll
    for (int r = 0; r < BATCH; ++r) {
        const float4 v = *reinterpret_cast<const float4*>(x + (size_t)r * IN_F + k0 + tid * 4);
        ushort4 p;
        p.x = __bfloat16_as_ushort(__float2bfloat16(v.x));
        p.y = __bfloat16_as_ushort(__float2bfloat16(v.y));
        p.z = __bfloat16_as_ushort(__float2bfloat16(v.z));
        p.w = __bfloat16_as_ushort(__float2bfloat16(v.w));
        *reinterpret_cast<ushort4*>(&xs[r][tid * 4]) = p;
    }
    __syncthreads();   // the ONLY barrier

    // A-frag: lane(m=mn, kgrp) holds x[m][k = s*32 + kgrp*8 + j], j=0..7 (16B LDS read)
    // B-frag: lane(n=mn, kgrp) holds w[row0+n][same k] (32B global read)
    // Identical per-lane k-addressing for A and B -> layout-safe (R5-validated).
    const int* qsrc = qw + (size_t)(row0 + mn) * IN_F + k0 + kgrp * 8;
    const unsigned short* asrc = &xs[mn][kgrp * 8];

    f32x4 acc = {0.f, 0.f, 0.f, 0.f};

    // prologue: step-0 operands
    int4 bca = *reinterpret_cast<const int4*>(qsrc);
    int4 bcb = *reinterpret_cast<const int4*>(qsrc + 4);
    bf16x8 ac = *reinterpret_cast<const bf16x8*>(asrc);

    #pragma unroll 1   // pin 1-step software pipeline; bounded registers
    for (int s = 0; s < NSTEPS; ++s) {
        int4 bna, bnb;
        bf16x8 an;
        const bool more = (s + 1 < NSTEPS);
        if (more) {
            bna = *reinterpret_cast<const int4*>(qsrc + (s + 1) * 32);
            bnb = *reinterpret_cast<const int4*>(qsrc + (s + 1) * 32 + 4);
            an  = *reinterpret_cast<const bf16x8*>(asrc + (s + 1) * 32);
        }

        // int4-valued weights (-8..7) are exact in bf16
        bf16x8 bw;
        bw[0] = __bfloat16_as_short(__float2bfloat16((float)bca.x));
        bw[1] = __bfloat16_as_short(__float2bfloat16((float)bca.y));
        bw[2] = __bfloat16_as_short(__float2bfloat16((float)bca.z));
        bw[3] = __bfloat16_as_short(__float2bfloat16((float)bca.w));
        bw[4] = __bfloat16_as_short(__float2bfloat16((float)bcb.x));
        bw[5] = __bfloat16_as_short(__float2bfloat16((float)bcb.y));
        bw[6] = __bfloat16_as_short(__float2bfloat16((float)bcb.z));
        bw[7] = __bfloat16_as_short(__float2bfloat16((float)bcb.w));

        acc = __builtin_amdgcn_mfma_f32_16x16x32_bf16(ac, bw, acc, 0, 0, 0);

        if (more) { bca = bna; bcb = bnb; ac = an; }
    }

    // C mapping (m89/R5-verified): col = lane&15 = n, row = kgrp*4 + v = batch m
    const float sc = scale[0];
    float* obase = out + row0 + mn;
    #pragma unroll
    for (int v = 0; v < 4; ++v) {
        const int m = kgrp * 4 + v;
        atomicAdd(obase + (size_t)m * OUT_F, acc[v] * sc);
    }
}

extern "C" void kernel_launch(void* const* d_in, const int* in_sizes, int n_in,
                              void* d_out, int out_size, void* d_ws, size_t ws_size,
                              hipStream_t stream) {
    const float* x     = (const float*)d_in[0];
    const int*   qw    = (const int*)d_in[1];
    const float* scale = (const float*)d_in[2];
    const float* bias  = (const float*)d_in[3];
    float*       out   = (float*)d_out;

    init_out_kernel<<<(BATCH * OUT_F) / 256, 256, 0, stream>>>(bias, out);

    dim3 grid((OUT_F / ROWS_PER_BLOCK) * KSPLIT);   // 128 x 8 = 1024 blocks = 4/CU
    gptq_mfma_kernel<<<grid, THREADS, 0, stream>>>(x, qw, scale, out);
}

// Round 9
// 52.649 us; speedup vs baseline: 2.4812x; 1.0392x over previous
//
#include <hip/hip_runtime.h>
#include <hip/hip_bf16.h>

#define IN_F  8192
#define OUT_F 8192
#define BATCH 16
#define KSPLIT 8
#define KCHUNK (IN_F / KSPLIT)     // 1024 k per block
#define NSTEPS (KCHUNK / 32)       // 32 mfma k-steps
#define THREADS 256                // 4 waves
#define ROWS_PER_BLOCK 64          // 4 waves x 16 rows
#define XPAD 8
#define XSTRIDE (KCHUNK + XPAD)
#define WS_NEEDED ((size_t)KSPLIT * BATCH * OUT_F * 4)

typedef __attribute__((ext_vector_type(8))) short bf16x8;
typedef __attribute__((ext_vector_type(4))) float f32x4;

// ---------- fallback path (R8): bias-init + atomics ----------
__global__ __launch_bounds__(256)
void init_out_kernel(const float* __restrict__ bias, float* __restrict__ out)
{
    const int i = blockIdx.x * 256 + threadIdx.x;
    out[i] = bias[i & (OUT_F - 1)];
}

// ---------- reduce: out[b][o] = scale * sum_k ws[k][b][o] + bias[o] ----------
__global__ __launch_bounds__(256)
void reduce_kernel(const float* __restrict__ ws,
                   const float* __restrict__ scale,
                   const float* __restrict__ bias,
                   float* __restrict__ out)
{
    const int idx = (blockIdx.x * 256 + threadIdx.x) * 4;   // over BATCH*OUT_F
    const int o   = idx & (OUT_F - 1);
    float4 s = {0.f, 0.f, 0.f, 0.f};
    #pragma unroll
    for (int k = 0; k < KSPLIT; ++k) {
        const float4 p = *reinterpret_cast<const float4*>(ws + (size_t)k * BATCH * OUT_F + idx);
        s.x += p.x; s.y += p.y; s.z += p.z; s.w += p.w;
    }
    const float sc = scale[0];
    const float4 bv = *reinterpret_cast<const float4*>(bias + o);
    float4 r;
    r.x = s.x * sc + bv.x; r.y = s.y * sc + bv.y;
    r.z = s.z * sc + bv.z; r.w = s.w * sc + bv.w;
    *reinterpret_cast<float4*>(out + idx) = r;
}

template<bool USE_WS>
__global__ __launch_bounds__(THREADS, 4)
void gptq_mfma_kernel(const float* __restrict__ x,
                      const int*  __restrict__ qw,
                      const float* __restrict__ scale,
                      float* __restrict__ dst)   // ws partials or out (fallback)
{
    __shared__ __align__(16) unsigned short xs[BATCH][XSTRIDE];   // ~33 KB

    const int tid  = threadIdx.x;
    const int lane = tid & 63;
    const int wave = tid >> 6;
    const int mn   = lane & 15;        // A: batch m    B: out-row n
    const int kgrp = lane >> 4;        // k-group 0..3
    const int kidx = blockIdx.x & (KSPLIT - 1);
    const int row0 = (blockIdx.x >> 3) * ROWS_PER_BLOCK + wave * 16;
    const int k0   = kidx * KCHUNK;

    // ---- stage x panel once (bf16), read-only afterwards ----
    #pragma unroll
    for (int r = 0; r < BATCH; ++r) {
        const float4 v = *reinterpret_cast<const float4*>(x + (size_t)r * IN_F + k0 + tid * 4);
        ushort4 p;
        p.x = __bfloat16_as_ushort(__float2bfloat16(v.x));
        p.y = __bfloat16_as_ushort(__float2bfloat16(v.y));
        p.z = __bfloat16_as_ushort(__float2bfloat16(v.z));
        p.w = __bfloat16_as_ushort(__float2bfloat16(v.w));
        *reinterpret_cast<ushort4*>(&xs[r][tid * 4]) = p;
    }
    __syncthreads();   // the ONLY barrier

    const int* qsrc = qw + (size_t)(row0 + mn) * IN_F + k0 + kgrp * 8;
    const unsigned short* asrc = &xs[mn][kgrp * 8];

    f32x4 acc = {0.f, 0.f, 0.f, 0.f};

    // prologue: operands for steps 0 and 1 (2-deep pipeline)
    int4 c0a = *reinterpret_cast<const int4*>(qsrc);
    int4 c0b = *reinterpret_cast<const int4*>(qsrc + 4);
    bf16x8 a0 = *reinterpret_cast<const bf16x8*>(asrc);
    int4 c1a = *reinterpret_cast<const int4*>(qsrc + 32);
    int4 c1b = *reinterpret_cast<const int4*>(qsrc + 36);
    bf16x8 a1 = *reinterpret_cast<const bf16x8*>(asrc + 32);

    #pragma unroll 1   // two steps per iteration, loads 2 steps ahead of use
    for (int s = 0; s < NSTEPS; s += 2) {
        int4 n0a, n0b, n1a, n1b;
        bf16x8 na0, na1;
        const bool m0 = (s + 2 < NSTEPS);
        const bool m1 = (s + 3 < NSTEPS);
        if (m0) {
            n0a = *reinterpret_cast<const int4*>(qsrc + (s + 2) * 32);
            n0b = *reinterpret_cast<const int4*>(qsrc + (s + 2) * 32 + 4);
            na0 = *reinterpret_cast<const bf16x8*>(asrc + (s + 2) * 32);
        }
        if (m1) {
            n1a = *reinterpret_cast<const int4*>(qsrc + (s + 3) * 32);
            n1b = *reinterpret_cast<const int4*>(qsrc + (s + 3) * 32 + 4);
            na1 = *reinterpret_cast<const bf16x8*>(asrc + (s + 3) * 32);
        }

        bf16x8 bw;
        bw[0] = __bfloat16_as_short(__float2bfloat16((float)c0a.x));
        bw[1] = __bfloat16_as_short(__float2bfloat16((float)c0a.y));
        bw[2] = __bfloat16_as_short(__float2bfloat16((float)c0a.z));
        bw[3] = __bfloat16_as_short(__float2bfloat16((float)c0a.w));
        bw[4] = __bfloat16_as_short(__float2bfloat16((float)c0b.x));
        bw[5] = __bfloat16_as_short(__float2bfloat16((float)c0b.y));
        bw[6] = __bfloat16_as_short(__float2bfloat16((float)c0b.z));
        bw[7] = __bfloat16_as_short(__float2bfloat16((float)c0b.w));
        acc = __builtin_amdgcn_mfma_f32_16x16x32_bf16(a0, bw, acc, 0, 0, 0);

        bw[0] = __bfloat16_as_short(__float2bfloat16((float)c1a.x));
        bw[1] = __bfloat16_as_short(__float2bfloat16((float)c1a.y));
        bw[2] = __bfloat16_as_short(__float2bfloat16((float)c1a.z));
        bw[3] = __bfloat16_as_short(__float2bfloat16((float)c1a.w));
        bw[4] = __bfloat16_as_short(__float2bfloat16((float)c1b.x));
        bw[5] = __bfloat16_as_short(__float2bfloat16((float)c1b.y));
        bw[6] = __bfloat16_as_short(__float2bfloat16((float)c1b.z));
        bw[7] = __bfloat16_as_short(__float2bfloat16((float)c1b.w));
        acc = __builtin_amdgcn_mfma_f32_16x16x32_bf16(a1, bw, acc, 0, 0, 0);

        if (m0) { c0a = n0a; c0b = n0b; a0 = na0; }
        if (m1) { c1a = n1a; c1b = n1b; a1 = na1; }
    }

    // C mapping (m89/R5/R8-verified): col = mn = n, row = kgrp*4 + v = batch m
    const float sc = scale[0];
    #pragma unroll
    for (int v = 0; v < 4; ++v) {
        const int m = kgrp * 4 + v;
        if (USE_WS) {
            // partials: ws[kidx][m][row0+mn]  (plain coalesced store, no RMW)
            dst[(size_t)kidx * BATCH * OUT_F + (size_t)m * OUT_F + row0 + mn] = acc[v];
        } else {
            atomicAdd(dst + (size_t)m * OUT_F + row0 + mn, acc[v] * sc);
        }
    }
}

extern "C" void kernel_launch(void* const* d_in, const int* in_sizes, int n_in,
                              void* d_out, int out_size, void* d_ws, size_t ws_size,
                              hipStream_t stream) {
    const float* x     = (const float*)d_in[0];
    const int*   qw    = (const int*)d_in[1];
    const float* scale = (const float*)d_in[2];
    const float* bias  = (const float*)d_in[3];
    float*       out   = (float*)d_out;
    float*       ws    = (float*)d_ws;

    dim3 grid((OUT_F / ROWS_PER_BLOCK) * KSPLIT);   // 128 x 8 = 1024 blocks = 4/CU

    if (ws_size >= WS_NEEDED) {
        gptq_mfma_kernel<true><<<grid, THREADS, 0, stream>>>(x, qw, scale, ws);
        reduce_kernel<<<(BATCH * OUT_F) / 4 / 256, 256, 0, stream>>>(ws, scale, bias, out);
    } else {
        init_out_kernel<<<(BATCH * OUT_F) / 256, 256, 0, stream>>>(bias, out);
        gptq_mfma_kernel<false><<<grid, THREADS, 0, stream>>>(x, qw, scale, out);
    }
}

// Round 10
// 51.594 us; speedup vs baseline: 2.5320x; 1.0205x over previous
//
#include <hip/hip_runtime.h>
#include <hip/hip_bf16.h>

#define IN_F  8192
#define OUT_F 8192
#define BATCH 16
#define KSPLIT 16
#define KCHUNK (IN_F / KSPLIT)     // 512 k per block
#define NSTEPS (KCHUNK / 32)       // 16 mfma k-steps
#define THREADS 256                // 4 waves
#define ROWS_PER_BLOCK 64          // 4 waves x 16 rows
#define XPAD 8
#define XSTRIDE (KCHUNK + XPAD)    // 520 shorts
#define WS_NEEDED ((size_t)KSPLIT * BATCH * OUT_F * 4)   // 8 MB

typedef __attribute__((ext_vector_type(8))) short bf16x8;
typedef __attribute__((ext_vector_type(4))) float f32x4;

// ---------- fallback path: bias-init + atomics ----------
__global__ __launch_bounds__(256)
void init_out_kernel(const float* __restrict__ bias, float* __restrict__ out)
{
    const int i = blockIdx.x * 256 + threadIdx.x;
    out[i] = bias[i & (OUT_F - 1)];
}

// ---------- reduce: out[b][o] = scale * sum_k ws[k][b][o] + bias[o] ----------
__global__ __launch_bounds__(256)
void reduce_kernel(const float* __restrict__ ws,
                   const float* __restrict__ scale,
                   const float* __restrict__ bias,
                   float* __restrict__ out)
{
    const int idx = (blockIdx.x * 256 + threadIdx.x) * 4;   // over BATCH*OUT_F
    const int o   = idx & (OUT_F - 1);
    float4 s = {0.f, 0.f, 0.f, 0.f};
    #pragma unroll
    for (int k = 0; k < KSPLIT; ++k) {
        const float4 p = *reinterpret_cast<const float4*>(ws + (size_t)k * BATCH * OUT_F + idx);
        s.x += p.x; s.y += p.y; s.z += p.z; s.w += p.w;
    }
    const float sc = scale[0];
    const float4 bv = *reinterpret_cast<const float4*>(bias + o);
    float4 r;
    r.x = s.x * sc + bv.x; r.y = s.y * sc + bv.y;
    r.z = s.z * sc + bv.z; r.w = s.w * sc + bv.w;
    *reinterpret_cast<float4*>(out + idx) = r;
}

template<bool USE_WS>
__global__ __launch_bounds__(THREADS, 8)   // cap 64 VGPR -> 8 blocks/CU
void gptq_mfma_kernel(const float* __restrict__ x,
                      const int*  __restrict__ qw,
                      const float* __restrict__ scale,
                      float* __restrict__ dst)
{
    __shared__ __align__(16) unsigned short xs[BATCH][XSTRIDE];   // 16.6 KB

    const int tid  = threadIdx.x;
    const int lane = tid & 63;
    const int wave = tid >> 6;
    const int mn   = lane & 15;        // A: batch m    B: out-row n
    const int kgrp = lane >> 4;        // k-group 0..3
    const int kidx = blockIdx.x & (KSPLIT - 1);
    const int row0 = (blockIdx.x >> 4) * ROWS_PER_BLOCK + wave * 16;
    const int k0   = kidx * KCHUNK;

    const int* qsrc = qw + (size_t)(row0 + mn) * IN_F + k0 + kgrp * 8;

    // ---- prologue weight loads FIRST (independent of LDS): overlap the stage ----
    int4 ca = *reinterpret_cast<const int4*>(qsrc);
    int4 cb = *reinterpret_cast<const int4*>(qsrc + 4);

    // ---- stage x panel once (bf16): row = 512 f32 = 256 threads x float2 ----
    #pragma unroll
    for (int r = 0; r < BATCH; ++r) {
        const float2 v = *reinterpret_cast<const float2*>(x + (size_t)r * IN_F + k0 + tid * 2);
        unsigned int p = (__bfloat16_as_ushort(__float2bfloat16(v.y)) << 16)
                       |  __bfloat16_as_ushort(__float2bfloat16(v.x));
        *reinterpret_cast<unsigned int*>(&xs[r][tid * 2]) = p;
    }
    __syncthreads();   // the ONLY barrier

    const unsigned short* asrc = &xs[mn][kgrp * 8];
    bf16x8 ac = *reinterpret_cast<const bf16x8*>(asrc);

    f32x4 acc = {0.f, 0.f, 0.f, 0.f};

    #pragma unroll 1   // 1-deep pipeline; bounded registers (<=64)
    for (int s = 0; s < NSTEPS; ++s) {
        int4 na, nb;
        bf16x8 an;
        const bool more = (s + 1 < NSTEPS);
        if (more) {
            na = *reinterpret_cast<const int4*>(qsrc + (s + 1) * 32);
            nb = *reinterpret_cast<const int4*>(qsrc + (s + 1) * 32 + 4);
            an = *reinterpret_cast<const bf16x8*>(asrc + (s + 1) * 32);
        }

        bf16x8 bw;   // int4-valued weights (-8..7) are exact in bf16
        bw[0] = __bfloat16_as_short(__float2bfloat16((float)ca.x));
        bw[1] = __bfloat16_as_short(__float2bfloat16((float)ca.y));
        bw[2] = __bfloat16_as_short(__float2bfloat16((float)ca.z));
        bw[3] = __bfloat16_as_short(__float2bfloat16((float)ca.w));
        bw[4] = __bfloat16_as_short(__float2bfloat16((float)cb.x));
        bw[5] = __bfloat16_as_short(__float2bfloat16((float)cb.y));
        bw[6] = __bfloat16_as_short(__float2bfloat16((float)cb.z));
        bw[7] = __bfloat16_as_short(__float2bfloat16((float)cb.w));

        acc = __builtin_amdgcn_mfma_f32_16x16x32_bf16(ac, bw, acc, 0, 0, 0);

        if (more) { ca = na; cb = nb; ac = an; }
    }

    // C mapping (m89/R5/R8-verified): col = mn = n, row = kgrp*4 + v = batch m
    const float sc = scale[0];
    #pragma unroll
    for (int v = 0; v < 4; ++v) {
        const int m = kgrp * 4 + v;
        if (USE_WS) {
            dst[(size_t)kidx * BATCH * OUT_F + (size_t)m * OUT_F + row0 + mn] = acc[v];
        } else {
            atomicAdd(dst + (size_t)m * OUT_F + row0 + mn, acc[v] * sc);
        }
    }
}

extern "C" void kernel_launch(void* const* d_in, const int* in_sizes, int n_in,
                              void* d_out, int out_size, void* d_ws, size_t ws_size,
                              hipStream_t stream) {
    const float* x     = (const float*)d_in[0];
    const int*   qw    = (const int*)d_in[1];
    const float* scale = (const float*)d_in[2];
    const float* bias  = (const float*)d_in[3];
    float*       out   = (float*)d_out;
    float*       ws    = (float*)d_ws;

    dim3 grid((OUT_F / ROWS_PER_BLOCK) * KSPLIT);   // 128 x 16 = 2048 blocks = 8/CU

    if (ws_size >= WS_NEEDED) {
        gptq_mfma_kernel<true><<<grid, THREADS, 0, stream>>>(x, qw, scale, ws);
        reduce_kernel<<<(BATCH * OUT_F) / 4 / 256, 256, 0, stream>>>(ws, scale, bias, out);
    } else {
        init_out_kernel<<<(BATCH * OUT_F) / 256, 256, 0, stream>>>(bias, out);
        gptq_mfma_kernel<false><<<grid, THREADS, 0, stream>>>(x, qw, scale, out);
    }
}

// Round 11
// 50.928 us; speedup vs baseline: 2.5651x; 1.0131x over previous
//
#include <hip/hip_runtime.h>
#include <hip/hip_bf16.h>

#define IN_F  8192
#define OUT_F 8192
#define BATCH 16
#define KSPLIT 16
#define KCHUNK (IN_F / KSPLIT)     // 512 k per block
#define NSTEPS (KCHUNK / 32)       // 16 mfma k-steps
#define THREADS 256                // 4 waves
#define ROWS_PER_BLOCK 64          // 4 waves x 16 rows
#define XPAD 8
#define XSTRIDE (KCHUNK + XPAD)    // 520 shorts
#define WS_NEEDED ((size_t)KSPLIT * BATCH * OUT_F * 4)   // 8 MB

typedef __attribute__((ext_vector_type(8))) short bf16x8;
typedef __attribute__((ext_vector_type(4))) float f32x4;

// ---------- fallback path: bias-init + atomics ----------
__global__ __launch_bounds__(256)
void init_out_kernel(const float* __restrict__ bias, float* __restrict__ out)
{
    const int i = blockIdx.x * 256 + threadIdx.x;
    out[i] = bias[i & (OUT_F - 1)];
}

// ---------- reduce: out[b][o] = scale * sum_k ws[k][b][o] + bias[o] ----------
__global__ __launch_bounds__(256)
void reduce_kernel(const float* __restrict__ ws,
                   const float* __restrict__ scale,
                   const float* __restrict__ bias,
                   float* __restrict__ out)
{
    const int idx = (blockIdx.x * 256 + threadIdx.x) * 4;   // over BATCH*OUT_F
    const int o   = idx & (OUT_F - 1);
    float4 s = {0.f, 0.f, 0.f, 0.f};
    #pragma unroll
    for (int k = 0; k < KSPLIT; ++k) {
        const float4 p = *reinterpret_cast<const float4*>(ws + (size_t)k * BATCH * OUT_F + idx);
        s.x += p.x; s.y += p.y; s.z += p.z; s.w += p.w;
    }
    const float sc = scale[0];
    const float4 bv = *reinterpret_cast<const float4*>(bias + o);
    float4 r;
    r.x = s.x * sc + bv.x; r.y = s.y * sc + bv.y;
    r.z = s.z * sc + bv.z; r.w = s.w * sc + bv.w;
    *reinterpret_cast<float4*>(out + idx) = r;
}

template<bool USE_WS>
__global__ __launch_bounds__(THREADS, 8)   // cap 64 VGPR -> 8 blocks/CU
void gptq_mfma_kernel(const float* __restrict__ x,
                      const int*  __restrict__ qw,
                      const float* __restrict__ scale,
                      float* __restrict__ dst)
{
    __shared__ __align__(16) unsigned short xs[BATCH][XSTRIDE];   // 16.6 KB

    const int tid  = threadIdx.x;
    const int lane = tid & 63;
    const int wave = tid >> 6;
    const int mn   = lane & 15;        // A: batch m    B: out-row n
    const int kgrp = lane >> 4;        // k-group 0..3
    const int kidx = blockIdx.x & (KSPLIT - 1);
    const int rowgrp = blockIdx.x >> 4;
    const int row0 = rowgrp * ROWS_PER_BLOCK + wave * 16;
    const int k0   = kidx * KCHUNK;

    // per-block k-phase stagger: same-kidx blocks start at different 128B
    // phases so their instantaneous address streams spread over all HBM
    // channel/bank phases instead of colliding in lockstep.
    const int s0 = rowgrp & (NSTEPS - 1);

    const int* qsrc = qw + (size_t)(row0 + mn) * IN_F + k0 + kgrp * 8;

    // ---- prologue weight loads FIRST (independent of LDS): overlap the stage ----
    int4 ca = *reinterpret_cast<const int4*>(qsrc + s0 * 32);
    int4 cb = *reinterpret_cast<const int4*>(qsrc + s0 * 32 + 4);

    // ---- stage x panel once (bf16): row = 512 f32 = 256 threads x float2 ----
    #pragma unroll
    for (int r = 0; r < BATCH; ++r) {
        const float2 v = *reinterpret_cast<const float2*>(x + (size_t)r * IN_F + k0 + tid * 2);
        unsigned int p = (__bfloat16_as_ushort(__float2bfloat16(v.y)) << 16)
                       |  __bfloat16_as_ushort(__float2bfloat16(v.x));
        *reinterpret_cast<unsigned int*>(&xs[r][tid * 2]) = p;
    }
    __syncthreads();   // the ONLY barrier

    const unsigned short* asrc = &xs[mn][kgrp * 8];
    bf16x8 ac = *reinterpret_cast<const bf16x8*>(asrc + s0 * 32);

    f32x4 acc = {0.f, 0.f, 0.f, 0.f};

    int sidx = s0;
    #pragma unroll 1   // 1-deep pipeline; bounded registers (<=64)
    for (int t = 0; t < NSTEPS; ++t) {
        int4 na, nb;
        bf16x8 an;
        const bool more = (t + 1 < NSTEPS);
        const int snext = (sidx + 1) & (NSTEPS - 1);
        if (more) {
            na = *reinterpret_cast<const int4*>(qsrc + snext * 32);
            nb = *reinterpret_cast<const int4*>(qsrc + snext * 32 + 4);
            an = *reinterpret_cast<const bf16x8*>(asrc + snext * 32);
        }

        bf16x8 bw;   // int4-valued weights (-8..7) are exact in bf16
        bw[0] = __bfloat16_as_short(__float2bfloat16((float)ca.x));
        bw[1] = __bfloat16_as_short(__float2bfloat16((float)ca.y));
        bw[2] = __bfloat16_as_short(__float2bfloat16((float)ca.z));
        bw[3] = __bfloat16_as_short(__float2bfloat16((float)ca.w));
        bw[4] = __bfloat16_as_short(__float2bfloat16((float)cb.x));
        bw[5] = __bfloat16_as_short(__float2bfloat16((float)cb.y));
        bw[6] = __bfloat16_as_short(__float2bfloat16((float)cb.z));
        bw[7] = __bfloat16_as_short(__float2bfloat16((float)cb.w));

        acc = __builtin_amdgcn_mfma_f32_16x16x32_bf16(ac, bw, acc, 0, 0, 0);

        if (more) { ca = na; cb = nb; ac = an; }
        sidx = snext;
    }

    // C mapping (m89/R5/R8-verified): col = mn = n, row = kgrp*4 + v = batch m
    const float sc = scale[0];
    #pragma unroll
    for (int v = 0; v < 4; ++v) {
        const int m = kgrp * 4 + v;
        if (USE_WS) {
            dst[(size_t)kidx * BATCH * OUT_F + (size_t)m * OUT_F + row0 + mn] = acc[v];
        } else {
            atomicAdd(dst + (size_t)m * OUT_F + row0 + mn, acc[v] * sc);
        }
    }
}

extern "C" void kernel_launch(void* const* d_in, const int* in_sizes, int n_in,
                              void* d_out, int out_size, void* d_ws, size_t ws_size,
                              hipStream_t stream) {
    const float* x     = (const float*)d_in[0];
    const int*   qw    = (const int*)d_in[1];
    const float* scale = (const float*)d_in[2];
    const float* bias  = (const float*)d_in[3];
    float*       out   = (float*)d_out;
    float*       ws    = (float*)d_ws;

    dim3 grid((OUT_F / ROWS_PER_BLOCK) * KSPLIT);   // 128 x 16 = 2048 blocks = 8/CU

    if (ws_size >= WS_NEEDED) {
        gptq_mfma_kernel<true><<<grid, THREADS, 0, stream>>>(x, qw, scale, ws);
        reduce_kernel<<<(BATCH * OUT_F) / 4 / 256, 256, 0, stream>>>(ws, scale, bias, out);
    } else {
        init_out_kernel<<<(BATCH * OUT_F) / 256, 256, 0, stream>>>(bias, out);
        gptq_mfma_kernel<false><<<grid, THREADS, 0, stream>>>(x, qw, scale, out);
    }
}